// Round 7
// baseline (101.814 us; speedup 1.0000x reference)
//
#include <hip/hip_runtime.h>

typedef unsigned long long u64;

#define NIMG 4
#define H 256
#define W 256
#define NPIX (H*W)           // 65536 per image
#define NTOT (NIMG*NPIX)     // 262144
#define WPR 4                // u64 words per row (256 bits)
#define WPI (H*WPR)          // 1024 words per image
#define XT 8                 // columns per tile block (both branches)
#define NSKEL 8              // skeleton blocks (1 per branch-image)
#define NTILE 128            // tile blocks: 4 img x 32 col-tiles
#define NB (NSKEL+NTILE)     // 136 blocks: all co-resident (<=256 CUs)

// ---------------------------------------------------------------------------
// Bit-parallel morphology helpers. Bit b of word k = pixel x = 64k+b.
// Erode = AND over cross; OOB=1.  Dilate = OR over 3x3 box; OOB=0.
// (Matches lax.reduce_window 'SAME' with -inf padding: pad is identity.)
// ---------------------------------------------------------------------------
__device__ __forceinline__ void erode_from(const u64 S[][WPR], int y, u64 out[WPR]) {
  u64 c[WPR], up[WPR], dn[WPR];
#pragma unroll
  for (int k = 0; k < WPR; ++k) {
    c[k]  = S[y][k];
    up[k] = (y > 0)     ? S[y-1][k] : ~0ULL;
    dn[k] = (y < H-1)   ? S[y+1][k] : ~0ULL;
  }
#pragma unroll
  for (int k = 0; k < WPR; ++k) {
    u64 l = (c[k] << 1) | ((k > 0)     ? (c[k-1] >> 63) : 1ULL);
    u64 r = (c[k] >> 1) | ((k < WPR-1) ? (c[k+1] << 63) : 0x8000000000000000ULL);
    out[k] = c[k] & up[k] & dn[k] & l & r;
  }
}

__device__ __forceinline__ void dilate_from(const u64 S[][WPR], int y, u64 out[WPR]) {
  u64 v[WPR];
#pragma unroll
  for (int k = 0; k < WPR; ++k) {
    u64 a = S[y][k];
    if (y > 0)   a |= S[y-1][k];
    if (y < H-1) a |= S[y+1][k];
    v[k] = a;
  }
#pragma unroll
  for (int k = 0; k < WPR; ++k) {
    u64 l = (v[k] << 1) | ((k > 0)     ? (v[k-1] >> 63) : 0ULL);
    u64 r = (v[k] >> 1) | ((k < WPR-1) ? (v[k+1] << 63) : 0ULL);
    out[k] = v[k] | l | r;
  }
}

// ---------------------------------------------------------------------------
// Per-thread mask-row builders. NO cross-lane ops, NO ballot loop (round-2
// lesson: serial load->ballot chains are latency death; 16 independent
// vector loads per word pipeline freely). Pred mask uses x>0, which is
// EXACTLY q>0.5 for q = sigmoid(2*sigmoid(x)-1): expf monotone, expf(0)=1,
// and 2p-1 is exact by Sterbenz — bit-identical predicate to all prior
// rounds that computed q explicitly.
// ---------------------------------------------------------------------------
__device__ __forceinline__ void build_row_true(const int* __restrict__ img_base,
                                               int y, u64 out[WPR]) {
  const int4* s = (const int4*)(img_base + y * W);
#pragma unroll
  for (int k = 0; k < WPR; ++k) {
    u64 w = 0;
#pragma unroll
    for (int m = 0; m < 16; ++m) {
      int4 v = s[k*16 + m];
      unsigned nib = (unsigned)(v.x > 0) | ((unsigned)(v.y > 0) << 1)
                   | ((unsigned)(v.z > 0) << 2) | ((unsigned)(v.w > 0) << 3);
      w |= (u64)nib << (4*m);
    }
    out[k] = w;
  }
}

__device__ __forceinline__ void build_row_pred(const float* __restrict__ img_base,
                                               int y, u64 out[WPR]) {
  const float4* s = (const float4*)(img_base + y * W);
#pragma unroll
  for (int k = 0; k < WPR; ++k) {
    u64 w = 0;
#pragma unroll
    for (int m = 0; m < 16; ++m) {
      float4 v = s[k*16 + m];
      unsigned nib = (unsigned)(v.x > 0.0f) | ((unsigned)(v.y > 0.0f) << 1)
                   | ((unsigned)(v.z > 0.0f) << 2) | ((unsigned)(v.w > 0.0f) << 3);
      w |= (u64)nib << (4*m);
    }
    out[k] = w;
  }
}

// EDT pass over LDS mask MARR: phase 1 (horizontal clz/ctz) -> col2,
// phase 2 (vertical early-exit envelope) -> DIST[8] registers.
#define EDT_PASS(MARR, DIST)                                                   \
  {                                                                            \
    int y = t;                                                                 \
    u64 z[WPR];                                                                \
    _Pragma("unroll")                                                          \
    for (int k = 0; k < WPR; ++k) z[k] = ~MARR[y][k];   /* background bits */  \
    _Pragma("unroll")                                                          \
    for (int xx = 0; xx < XT; ++xx) {                                          \
      int x = x0 + xx;                                                         \
      int bx = x & 63;                                                         \
      int ld = 512;                                                            \
      {                                                                        \
        u64 w = z[kx] & ((bx == 63) ? ~0ULL : ((1ULL << (bx+1)) - 1ULL));      \
        for (int k = kx; ; ) {                                                 \
          if (w) { int pos = 63 - __builtin_clzll(w) + (k << 6); ld = x - pos; break; } \
          if (--k < 0) break;                                                  \
          w = z[k];                                                            \
        }                                                                      \
      }                                                                        \
      int rd = 512;                                                            \
      {                                                                        \
        u64 w = z[kx] & (~0ULL << bx);                                         \
        for (int k = kx; ; ) {                                                 \
          if (w) { int pos = __builtin_ctzll(w) + (k << 6); rd = pos - x; break; } \
          if (++k > WPR-1) break;                                              \
          w = z[k];                                                            \
        }                                                                      \
      }                                                                        \
      int g = min(ld, rd);                                                     \
      col2[y][xx] = (float)(g * g);                                            \
    }                                                                          \
  }                                                                            \
  __syncthreads();                                                             \
  _Pragma("unroll")                                                            \
  for (int j = 0; j < 8; ++j) {                                                \
    int y = yg * 8 + j;                                                        \
    float best = col2[y][xq];                                                  \
    for (int k = 1; k < H; ++k) {                                              \
      float k2 = (float)(k * k);                                               \
      if (k2 >= best) break;           /* no farther candidate improves */     \
      int ym = y - k, yd = y + k;                                              \
      if (ym >= 0) best = fminf(best, col2[ym][xq] + k2);                      \
      if (yd < H)  best = fminf(best, col2[yd][xq] + k2);                      \
    }                                                                          \
    (DIST)[j] = sqrtf(best);                                                   \
  }                                                                            \
  __syncthreads();

// ---------------------------------------------------------------------------
// SINGLE compute kernel. 136 blocks x 256 threads, plain launch.
// Init (sums/rmm/cnts) comes from a 160 B hipMemsetAsync before the launch;
// rmax = atomicMax over float bits (0-init = identity for >=0), rmin =
// atomicMax over ~bits (monotone-decreasing for >=0 floats; 0-init identity;
// readback = ~stored).
//  blocks 0..7   (skel): build own (branch,image) mask in LDS (per-thread
//                 row assembly) -> 10-iter bit-packed soft_skel -> skel_bits;
//                 ONE release fence + flag (round-4 proven); exit.
//  blocks 8..135 (tile): build BOTH branch masks of their image in LDS;
//                 EDT both branches (dist in regs); wait skel flags (fast
//                 side, ~0 spin); sc1-stage skel words; fused rmax/rmin
//                 atomics + per-image 32-block sub-barrier (clean-LLC
//                 atomics only — round-5 lesson: NO dirty-L2 grid barrier);
//                 q-phase over own 2048 px from regs/LDS (ppv recomputed);
//                 4 double atomics; last-of-128 finalizes.
// ---------------------------------------------------------------------------
__global__ void __launch_bounds__(256, 1) fused_kernel(
    const float* __restrict__ y_pred, const int* __restrict__ y_true,
    u64* __restrict__ skel_bits, unsigned* __restrict__ rmm_u,
    double* __restrict__ sums, unsigned* __restrict__ cnts,
    float* __restrict__ out) {
  __shared__ u64 SA[H][WPR];          // skel: ping buffer | tile: true mask
  __shared__ u64 SB[H][WPR];          // skel: pong buffer | tile: pred mask
  __shared__ float col2[H][XT + 1];
  __shared__ u64 srow_t[H];
  __shared__ u64 srow_p[H];
  __shared__ float redf[4][4];
  __shared__ unsigned smm[4];
  int t = threadIdx.x;

  if (blockIdx.x < NSKEL) {
    // ---- skel block: build mask row, then bit-packed soft_skel ----
    int bi  = blockIdx.x;               // branch*4+img
    int img = bi & 3;
    int y = t;
    u64 a[WPR], cur[WPR], e[WPR], d[WPR], sk[WPR];
    if (bi < 4) build_row_true(y_true + img*NPIX, y, a);
    else        build_row_pred(y_pred + img*NPIX, y, a);
#pragma unroll
    for (int k = 0; k < WPR; ++k) SA[y][k] = a[k];
    __syncthreads();
    erode_from(SA, y, e);                 // E1 = erode(a)
#pragma unroll
    for (int k = 0; k < WPR; ++k) SB[y][k] = e[k];
    __syncthreads();                      // SB visible; all SA reads complete
    dilate_from(SB, y, d);                // open(a)
#pragma unroll
    for (int k = 0; k < WPR; ++k) { sk[k] = a[k] & ~d[k]; cur[k] = e[k]; }
    u64 (*P)[WPR] = SB;                   // current erosion level E_k
    u64 (*Q)[WPR] = SA;                   // dead buffer
    for (int it = 0; it < 10; ++it) {     // levels 1..10
      erode_from(P, y, e);                // E_{k+1}
#pragma unroll
      for (int k = 0; k < WPR; ++k) Q[y][k] = e[k];   // overwrite dead data
      __syncthreads();                    // publish Q; P reads all done
      dilate_from(Q, y, d);               // open(E_k)
#pragma unroll
      for (int k = 0; k < WPR; ++k) { sk[k] |= cur[k] & ~d[k]; cur[k] = e[k]; }
      u64 (*T)[WPR] = P; P = Q; Q = T;
    }
    int base = bi * WPI;
#pragma unroll
    for (int k = 0; k < WPR; ++k) skel_bits[base + y*WPR + k] = sk[k];
    __syncthreads();                      // all stores issued + vmcnt drained
    if (t == 0) {
      __threadfence();                    // release: writeback XCD L2 (8 total)
      atomicAdd(&cnts[bi], 1u);           // per-(branch,image) flag
    }
    return;
  }

  // ===================== tile blocks (8..135) =====================
  int tb  = blockIdx.x - NSKEL;          // 0..127
  int img = tb >> 5;                     // 0..3
  int xt  = tb & 31;                     // 0..31
  int x0  = xt * XT;
  int kx  = x0 >> 6;                     // tile's 8 columns share this word
  int sh0 = x0 & 63;                     // <= 56
  int xq  = t & (XT - 1);                // phase-2/q column 0..7
  int yg  = t >> 3;                      // phase-2/q row group 0..31

  // ---- build BOTH branch masks for this image (per-thread row assembly) ----
  {
    u64 rt[WPR], rp[WPR];
    build_row_true(y_true + img*NPIX, t, rt);
    build_row_pred(y_pred + img*NPIX, t, rp);
#pragma unroll
    for (int k = 0; k < WPR; ++k) { SA[t][k] = rt[k]; SB[t][k] = rp[k]; }
  }
  __syncthreads();

  float dist_t[8], dist_p[8];
  EDT_PASS(SA, dist_t)                   // true branch
  EDT_PASS(SB, dist_p)                   // pred branch

  // --- round-4 handshake: wait for BOTH skel flags (fast side, ~0 spin) ---
  if (t == 0) {
    while (__hip_atomic_load(&cnts[img], __ATOMIC_RELAXED,
                             __HIP_MEMORY_SCOPE_AGENT) == 0u)
      __builtin_amdgcn_s_sleep(2);
    while (__hip_atomic_load(&cnts[4+img], __ATOMIC_RELAXED,
                             __HIP_MEMORY_SCOPE_AGENT) == 0u)
      __builtin_amdgcn_s_sleep(2);
  }
  __syncthreads();
  // stage skel words for this tile (sc1: bypass stale L2, LLC-coherent)
  srow_t[t] = __hip_atomic_load(&skel_bits[img*WPI + t*WPR + kx],
                                __ATOMIC_RELAXED, __HIP_MEMORY_SCOPE_AGENT);
  srow_p[t] = __hip_atomic_load(&skel_bits[(4+img)*WPI + t*WPR + kx],
                                __ATOMIC_RELAXED, __HIP_MEMORY_SCOPE_AGENT);
  __syncthreads();

  // --- fused rmax/rmin for BOTH branches (regs + LDS only) ---
  float vmax_t = 0.0f, vmin_t = 3.0e38f, vmax_p = 0.0f, vmin_p = 3.0e38f;
#pragma unroll
  for (int j = 0; j < 8; ++j) {
    int y = yg * 8 + j;
    int sb_t = (int)((srow_t[y] >> (sh0 + xq)) & 1ULL);
    int sb_p = (int)((srow_p[y] >> (sh0 + xq)) & 1ULL);
    float srt = sb_t ? dist_t[j] : 0.0f;  // skel_radius, true branch
    float srp = sb_p ? dist_p[j] : 0.0f;  // skel_radius, pred branch
    vmax_t = fmaxf(vmax_t, srt); vmin_t = fminf(vmin_t, srt);
    vmax_p = fmaxf(vmax_p, srp); vmin_p = fminf(vmin_p, srp);
  }
  for (int o = 32; o > 0; o >>= 1) {
    vmax_t = fmaxf(vmax_t, __shfl_down(vmax_t, o, 64));
    vmin_t = fminf(vmin_t, __shfl_down(vmin_t, o, 64));
    vmax_p = fmaxf(vmax_p, __shfl_down(vmax_p, o, 64));
    vmin_p = fminf(vmin_p, __shfl_down(vmin_p, o, 64));
  }
  int wave = t >> 6, lane = t & 63;
  if (lane == 0) { redf[wave][0]=vmax_t; redf[wave][1]=vmin_t;
                   redf[wave][2]=vmax_p; redf[wave][3]=vmin_p; }
  __syncthreads();
  if (t == 0) {
    float mxt=redf[0][0], mnt=redf[0][1], mxp=redf[0][2], mnp=redf[0][3];
    for (int wv = 1; wv < 4; ++wv) {
      mxt = fmaxf(mxt, redf[wv][0]); mnt = fminf(mnt, redf[wv][1]);
      mxp = fmaxf(mxp, redf[wv][2]); mnp = fminf(mnp, redf[wv][3]);
    }
    // max via bits (0-init identity); min via ~bits (0-init identity)
    atomicMax(&rmm_u[img*2 + 0],     __float_as_uint(mxt));
    atomicMax(&rmm_u[img*2 + 1],     ~__float_as_uint(mnt));
    atomicMax(&rmm_u[(4+img)*2 + 0], __float_as_uint(mxp));
    atomicMax(&rmm_u[(4+img)*2 + 1], ~__float_as_uint(mnp));
    // per-image sub-barrier: release RMW orders the atomics above (all at
    // LLC already — nothing dirty in L2; round-5's wbl2 disaster avoided)
    __hip_atomic_fetch_add(&cnts[10+img], 1u, __ATOMIC_RELEASE,
                           __HIP_MEMORY_SCOPE_AGENT);
    while (__hip_atomic_load(&cnts[10+img], __ATOMIC_RELAXED,
                             __HIP_MEMORY_SCOPE_AGENT) < 32u)
      __builtin_amdgcn_s_sleep(2);
  }
  __syncthreads();
  if (t < 4) {
    int idx = (t < 2) ? (img*2 + t) : ((4+img)*2 + (t-2));
    smm[t] = __hip_atomic_load(&rmm_u[idx], __ATOMIC_RELAXED,
                               __HIP_MEMORY_SCOPE_AGENT);
  }
  __syncthreads();
  float rmax_t = fmaxf(__uint_as_float( smm[0]), 1.0f);
  float rmin_t = fmaxf(__uint_as_float(~smm[1]), 1.0f);
  float rmax_p = fmaxf(__uint_as_float( smm[2]), 1.0f);
  float rmin_p = fmaxf(__uint_as_float(~smm[3]), 1.0f);

  // --- q-phase over this block's OWN 2048 pixels (dist in regs) ---
  float q1 = 0.f, q2 = 0.f, q3 = 0.f, q4 = 0.f;
#pragma unroll
  for (int j = 0; j < 8; ++j) {
    int y = yg * 8 + j;
    float xv = y_pred[img*NPIX + y*W + x0 + xq];
    float p = 1.0f / (1.0f + expf(-xv));
    float ppv = 1.0f / (1.0f + expf(-(2.0f * p - 1.0f)));  // exact ref expr
    int b = sh0 + xq;
    int m_t  = (int)((SA[y][kx] >> b) & 1ULL);   // true mask from LDS
    int s_t  = (int)((srow_t[y] >> b) & 1ULL);
    int s_pb = (int)((srow_p[y] >> b) & 1ULL);
    // --- true branch (binary) ---
    float distances_t = m_t ? dist_t[j] : 0.0f;
    float skelrad_t   = s_t ? distances_t : 0.0f;
    float dmn_t = fminf(distances_t, rmax_t) / rmax_t;
    float srn_t = skelrad_t / rmax_t;
    float In_t  = s_t ? (rmax_t - skelrad_t + rmin_t) / rmax_t : 0.0f;
    float q_vl   = m_t ? dmn_t : 0.0f;
    float q_slvl = m_t ? srn_t : 0.0f;
    float q_sl   = s_t ? In_t  : 0.0f;
    // --- pred branch (probabilistic) ---
    float skel_in_p = s_pb ? ppv : 0.0f;      // skel_pred_prob
    bool msk_p = ppv > 0.5f;
    bool sk_p  = skel_in_p > 0.5f;
    float distances_p = msk_p ? dist_p[j] : 0.0f;
    float skelrad_p   = sk_p ? distances_p : 0.0f;
    float dmn_p = fminf(distances_p, rmax_p) / rmax_p;
    float srn_p = skelrad_p / rmax_p;
    float In_p  = sk_p ? (rmax_p - skelrad_p + rmin_p) / rmax_p : 0.0f;
    float q_vp   = dmn_p * ppv;
    float q_spvp = srn_p * ppv;
    float q_sp   = In_p * skel_in_p;
    q1 += q_sp * q_vl;
    q2 += (q_spvp != 0.0f && q_slvl == 0.0f) ? q_spvp * q_sp : q_slvl * q_sp;
    q3 += q_sl * q_vp;
    q4 += (q_slvl != 0.0f && q_spvp == 0.0f) ? q_slvl * q_sl : q_spvp * q_sl;
  }
  for (int o = 32; o > 0; o >>= 1) {
    q1 += __shfl_down(q1, o, 64);
    q2 += __shfl_down(q2, o, 64);
    q3 += __shfl_down(q3, o, 64);
    q4 += __shfl_down(q4, o, 64);
  }
  if (lane == 0) { redf[wave][0]=q1; redf[wave][1]=q2; redf[wave][2]=q3; redf[wave][3]=q4; }
  __syncthreads();
  if (t == 0) {
    float a0=0,a1=0,a2=0,a3=0;
    for (int wv = 0; wv < 4; ++wv) {
      a0 += redf[wv][0]; a1 += redf[wv][1]; a2 += redf[wv][2]; a3 += redf[wv][3];
    }
    atomicAdd(&sums[0], (double)a0);
    atomicAdd(&sums[1], (double)a1);
    atomicAdd(&sums[2], (double)a2);
    atomicAdd(&sums[3], (double)a3);
    __threadfence();                    // publish sums before counting done
    unsigned c = atomicAdd(&cnts[8], 1u);
    if (c == NTILE - 1) {               // last block finalizes (device-scope
      double s0 = atomicAdd(&sums[0], 0.0);   // atomic loads for coherence)
      double s1 = atomicAdd(&sums[1], 0.0);
      double s2 = atomicAdd(&sums[2], 0.0);
      double s3 = atomicAdd(&sums[3], 0.0);
      double wp  = (s0 + 1.0) / (s1 + 1.0);
      double wsn = (s2 + 1.0) / (s3 + 1.0);
      out[0] = (float)(1.0 - 2.0 * (wp * wsn) / (wp + wsn));
    }
  }
}

extern "C" void kernel_launch(void* const* d_in, const int* in_sizes, int n_in,
                              void* d_out, int out_size, void* d_ws, size_t ws_size,
                              hipStream_t stream) {
  (void)in_sizes; (void)n_in; (void)out_size; (void)ws_size;
  const float* y_pred = (const float*)d_in[0];
  const int*   y_true = (const int*)d_in[1];
  float* out = (float*)d_out;
  char* ws = (char*)d_ws;

  // workspace layout (bytes) — only skel_bits + 160 B of control state
  u64*   skel_bits = (u64*)  (ws + 0);          // 8192 u64 (65,536 B)
  unsigned* rmm_u  = (unsigned*)(ws + 65536);   // 16 u32: [bi*2]=max bits, [bi*2+1]=max ~bits (min)
  double* sums     = (double*)(ws + 65600);     // 4 d (8-aligned)
  unsigned* cnts   = (unsigned*)(ws + 65632);   // [0..7] skel flags, [8] done, [10..13] img barriers

  // zero-init all control state (graph-safe; rmax/rmin encodings chosen so
  // that 0 is the atomic identity — see kernel comment)
  hipMemsetAsync(ws + 65536, 0, 160, stream);
  fused_kernel<<<NB, 256, 0, stream>>>(y_pred, y_true, skel_bits, rmm_u, sums, cnts, out);
}

// Round 8
// 93.799 us; speedup vs baseline: 1.0854x; 1.0854x over previous
//
#include <hip/hip_runtime.h>

typedef unsigned long long u64;

#define NIMG 4
#define H 256
#define W 256
#define NPIX (H*W)           // 65536 per image
#define NTOT (NIMG*NPIX)     // 262144
#define WPR 4                // u64 words per row (256 bits)
#define WPI (H*WPR)          // 1024 words per image
#define XT 8                 // columns per tile block (both branches)
#define NSKEL 8              // skeleton blocks (1 per branch-image)
#define NTILE 128            // tile blocks: 4 img x 32 col-tiles
#define NB (NSKEL+NTILE)     // 136 blocks: all co-resident (<=256 CUs)

// ---------------------------------------------------------------------------
// Bit-parallel morphology helpers. Bit b of word k = pixel x = 64k+b.
// Erode = AND over cross; OOB=1.  Dilate = OR over 3x3 box; OOB=0.
// ---------------------------------------------------------------------------
__device__ __forceinline__ void erode_from(const u64 S[][WPR], int y, u64 out[WPR]) {
  u64 c[WPR], up[WPR], dn[WPR];
#pragma unroll
  for (int k = 0; k < WPR; ++k) {
    c[k]  = S[y][k];
    up[k] = (y > 0)     ? S[y-1][k] : ~0ULL;
    dn[k] = (y < H-1)   ? S[y+1][k] : ~0ULL;
  }
#pragma unroll
  for (int k = 0; k < WPR; ++k) {
    u64 l = (c[k] << 1) | ((k > 0)     ? (c[k-1] >> 63) : 1ULL);
    u64 r = (c[k] >> 1) | ((k < WPR-1) ? (c[k+1] << 63) : 0x8000000000000000ULL);
    out[k] = c[k] & up[k] & dn[k] & l & r;
  }
}

__device__ __forceinline__ void dilate_from(const u64 S[][WPR], int y, u64 out[WPR]) {
  u64 v[WPR];
#pragma unroll
  for (int k = 0; k < WPR; ++k) {
    u64 a = S[y][k];
    if (y > 0)   a |= S[y-1][k];
    if (y < H-1) a |= S[y+1][k];
    v[k] = a;
  }
#pragma unroll
  for (int k = 0; k < WPR; ++k) {
    u64 l = (v[k] << 1) | ((k > 0)     ? (v[k-1] >> 63) : 0ULL);
    u64 r = (v[k] >> 1) | ((k < WPR-1) ? (v[k+1] << 63) : 0ULL);
    out[k] = v[k] | l | r;
  }
}

// ---------------------------------------------------------------------------
// COALESCED mask build (round-7 lesson: per-thread ROW reads are 64-line
// gathers -> 49us kernel; lane i must touch pixel i). Thread t handles 8
// consecutive px per iteration: int4/float4 loads are lane-contiguous
// (2 KB/wave), predicate byte stored straight into the bitmask byte
// position ((uchar*)S)[px>>3] — byte j of word (y,k) IS pixel byte px>>3,
// so no ballot, no pack phase. Pred predicate x>0 == q>0.5 exactly
// (expf monotone, expf(0)=1, Sterbenz) — proven bit-exact in r7.
// ---------------------------------------------------------------------------
#define BUILD_TRUE(DSTB, IMGBASE)                                              \
  {                                                                            \
    const int4* s4 = (const int4*)(IMGBASE);                                   \
    _Pragma("unroll 4")                                                        \
    for (int it = 0; it < 32; ++it) {                                          \
      int base = it * 2048 + t * 8;                                            \
      int4 a0 = s4[(base >> 2)];                                               \
      int4 a1 = s4[(base >> 2) + 1];                                           \
      unsigned bv = (unsigned)(a0.x > 0)        | ((unsigned)(a0.y > 0) << 1)  \
                  | ((unsigned)(a0.z > 0) << 2) | ((unsigned)(a0.w > 0) << 3)  \
                  | ((unsigned)(a1.x > 0) << 4) | ((unsigned)(a1.y > 0) << 5)  \
                  | ((unsigned)(a1.z > 0) << 6) | ((unsigned)(a1.w > 0) << 7); \
      (DSTB)[base >> 3] = (unsigned char)bv;                                   \
    }                                                                          \
  }

#define BUILD_PRED(DSTB, IMGBASE)                                              \
  {                                                                            \
    const float4* s4 = (const float4*)(IMGBASE);                               \
    _Pragma("unroll 4")                                                        \
    for (int it = 0; it < 32; ++it) {                                          \
      int base = it * 2048 + t * 8;                                            \
      float4 f0 = s4[(base >> 2)];                                             \
      float4 f1 = s4[(base >> 2) + 1];                                         \
      unsigned bv = (unsigned)(f0.x > 0.0f)        | ((unsigned)(f0.y > 0.0f) << 1)  \
                  | ((unsigned)(f0.z > 0.0f) << 2) | ((unsigned)(f0.w > 0.0f) << 3)  \
                  | ((unsigned)(f1.x > 0.0f) << 4) | ((unsigned)(f1.y > 0.0f) << 5)  \
                  | ((unsigned)(f1.z > 0.0f) << 6) | ((unsigned)(f1.w > 0.0f) << 7); \
      (DSTB)[base >> 3] = (unsigned char)bv;                                   \
    }                                                                          \
  }

// EDT pass over LDS mask MARR: phase 1 (horizontal clz/ctz) -> col2,
// phase 2 (vertical early-exit envelope) -> DIST[8] registers.
#define EDT_PASS(MARR, DIST)                                                   \
  {                                                                            \
    int y = t;                                                                 \
    u64 z[WPR];                                                                \
    _Pragma("unroll")                                                          \
    for (int k = 0; k < WPR; ++k) z[k] = ~MARR[y][k];   /* background bits */  \
    _Pragma("unroll")                                                          \
    for (int xx = 0; xx < XT; ++xx) {                                          \
      int x = x0 + xx;                                                         \
      int bx = x & 63;                                                         \
      int ld = 512;                                                            \
      {                                                                        \
        u64 w = z[kx] & ((bx == 63) ? ~0ULL : ((1ULL << (bx+1)) - 1ULL));      \
        for (int k = kx; ; ) {                                                 \
          if (w) { int pos = 63 - __builtin_clzll(w) + (k << 6); ld = x - pos; break; } \
          if (--k < 0) break;                                                  \
          w = z[k];                                                            \
        }                                                                      \
      }                                                                        \
      int rd = 512;                                                            \
      {                                                                        \
        u64 w = z[kx] & (~0ULL << bx);                                         \
        for (int k = kx; ; ) {                                                 \
          if (w) { int pos = __builtin_ctzll(w) + (k << 6); rd = pos - x; break; } \
          if (++k > WPR-1) break;                                              \
          w = z[k];                                                            \
        }                                                                      \
      }                                                                        \
      int g = min(ld, rd);                                                     \
      col2[y][xx] = (float)(g * g);                                            \
    }                                                                          \
  }                                                                            \
  __syncthreads();                                                             \
  _Pragma("unroll")                                                            \
  for (int j = 0; j < 8; ++j) {                                                \
    int y = yg * 8 + j;                                                        \
    float best = col2[y][xq];                                                  \
    for (int k = 1; k < H; ++k) {                                              \
      float k2 = (float)(k * k);                                               \
      if (k2 >= best) break;           /* no farther candidate improves */     \
      int ym = y - k, yd = y + k;                                              \
      if (ym >= 0) best = fminf(best, col2[ym][xq] + k2);                      \
      if (yd < H)  best = fminf(best, col2[yd][xq] + k2);                      \
    }                                                                          \
    (DIST)[j] = sqrtf(best);                                                   \
  }                                                                            \
  __syncthreads();

// ---------------------------------------------------------------------------
// SINGLE compute kernel. 136 blocks x 256 threads (round-7 structure,
// round-8 coalesced builders). Init from 160 B hipMemsetAsync; rmax =
// atomicMax(bits), rmin = atomicMax(~bits) — 0-init is the identity.
// ---------------------------------------------------------------------------
__global__ void __launch_bounds__(256, 1) fused_kernel(
    const float* __restrict__ y_pred, const int* __restrict__ y_true,
    u64* __restrict__ skel_bits, unsigned* __restrict__ rmm_u,
    double* __restrict__ sums, unsigned* __restrict__ cnts,
    float* __restrict__ out) {
  __shared__ u64 SA[H][WPR];          // skel: ping buffer | tile: true mask
  __shared__ u64 SB[H][WPR];          // skel: pong buffer | tile: pred mask
  __shared__ float col2[H][XT + 1];
  __shared__ u64 srow_t[H];
  __shared__ u64 srow_p[H];
  __shared__ float redf[4][4];
  __shared__ unsigned smm[4];
  int t = threadIdx.x;

  if (blockIdx.x < NSKEL) {
    // ---- skel block: coalesced mask build, then bit-packed soft_skel ----
    int bi  = blockIdx.x;               // branch*4+img
    int img = bi & 3;
    int y = t;
    unsigned char* sab = (unsigned char*)SA;
    if (bi < 4) { BUILD_TRUE(sab, y_true + img*NPIX) }
    else        { BUILD_PRED(sab, y_pred + img*NPIX) }
    __syncthreads();
    u64 a[WPR], cur[WPR], e[WPR], d[WPR], sk[WPR];
#pragma unroll
    for (int k = 0; k < WPR; ++k) a[k] = SA[y][k];
    erode_from(SA, y, e);                 // E1 = erode(a)
    __syncthreads();                      // all SA reads complete before SB?? (SB independent) — keep order safe
#pragma unroll
    for (int k = 0; k < WPR; ++k) SB[y][k] = e[k];
    __syncthreads();                      // SB visible
    dilate_from(SB, y, d);                // open(a)
#pragma unroll
    for (int k = 0; k < WPR; ++k) { sk[k] = a[k] & ~d[k]; cur[k] = e[k]; }
    u64 (*P)[WPR] = SB;                   // current erosion level E_k
    u64 (*Q)[WPR] = SA;                   // dead buffer
    for (int it = 0; it < 10; ++it) {     // levels 1..10
      erode_from(P, y, e);                // E_{k+1}
#pragma unroll
      for (int k = 0; k < WPR; ++k) Q[y][k] = e[k];   // overwrite dead data
      __syncthreads();                    // publish Q; P reads all done
      dilate_from(Q, y, d);               // open(E_k)
#pragma unroll
      for (int k = 0; k < WPR; ++k) { sk[k] |= cur[k] & ~d[k]; cur[k] = e[k]; }
      u64 (*T)[WPR] = P; P = Q; Q = T;
    }
    int base = bi * WPI;
#pragma unroll
    for (int k = 0; k < WPR; ++k) skel_bits[base + y*WPR + k] = sk[k];
    __syncthreads();                      // all stores issued + vmcnt drained
    if (t == 0) {
      __threadfence();                    // release: writeback XCD L2 (8 total)
      atomicAdd(&cnts[bi], 1u);           // per-(branch,image) flag
    }
    return;
  }

  // ===================== tile blocks (8..135) =====================
  int tb  = blockIdx.x - NSKEL;          // 0..127
  int img = tb >> 5;                     // 0..3
  int xt  = tb & 31;                     // 0..31
  int x0  = xt * XT;
  int kx  = x0 >> 6;                     // tile's 8 columns share this word
  int sh0 = x0 & 63;                     // <= 56
  int xq  = t & (XT - 1);                // phase-2/q column 0..7
  int yg  = t >> 3;                      // phase-2/q row group 0..31

  // ---- build BOTH branch masks for this image (coalesced byte build) ----
  {
    unsigned char* sab = (unsigned char*)SA;
    unsigned char* sbb = (unsigned char*)SB;
    BUILD_TRUE(sab, y_true + img*NPIX)
    BUILD_PRED(sbb, y_pred + img*NPIX)
  }
  __syncthreads();

  float dist_t[8], dist_p[8];
  EDT_PASS(SA, dist_t)                   // true branch
  EDT_PASS(SB, dist_p)                   // pred branch

  // --- round-4 handshake: wait for BOTH skel flags (fast side, ~0 spin) ---
  if (t == 0) {
    while (__hip_atomic_load(&cnts[img], __ATOMIC_RELAXED,
                             __HIP_MEMORY_SCOPE_AGENT) == 0u)
      __builtin_amdgcn_s_sleep(2);
    while (__hip_atomic_load(&cnts[4+img], __ATOMIC_RELAXED,
                             __HIP_MEMORY_SCOPE_AGENT) == 0u)
      __builtin_amdgcn_s_sleep(2);
  }
  __syncthreads();
  // stage skel words for this tile (sc1: bypass stale L2, LLC-coherent)
  srow_t[t] = __hip_atomic_load(&skel_bits[img*WPI + t*WPR + kx],
                                __ATOMIC_RELAXED, __HIP_MEMORY_SCOPE_AGENT);
  srow_p[t] = __hip_atomic_load(&skel_bits[(4+img)*WPI + t*WPR + kx],
                                __ATOMIC_RELAXED, __HIP_MEMORY_SCOPE_AGENT);
  __syncthreads();

  // --- fused rmax/rmin for BOTH branches (regs + LDS only) ---
  float vmax_t = 0.0f, vmin_t = 3.0e38f, vmax_p = 0.0f, vmin_p = 3.0e38f;
#pragma unroll
  for (int j = 0; j < 8; ++j) {
    int y = yg * 8 + j;
    int sb_t = (int)((srow_t[y] >> (sh0 + xq)) & 1ULL);
    int sb_p = (int)((srow_p[y] >> (sh0 + xq)) & 1ULL);
    float srt = sb_t ? dist_t[j] : 0.0f;  // skel_radius, true branch
    float srp = sb_p ? dist_p[j] : 0.0f;  // skel_radius, pred branch
    vmax_t = fmaxf(vmax_t, srt); vmin_t = fminf(vmin_t, srt);
    vmax_p = fmaxf(vmax_p, srp); vmin_p = fminf(vmin_p, srp);
  }
  for (int o = 32; o > 0; o >>= 1) {
    vmax_t = fmaxf(vmax_t, __shfl_down(vmax_t, o, 64));
    vmin_t = fminf(vmin_t, __shfl_down(vmin_t, o, 64));
    vmax_p = fmaxf(vmax_p, __shfl_down(vmax_p, o, 64));
    vmin_p = fminf(vmin_p, __shfl_down(vmin_p, o, 64));
  }
  int wave = t >> 6, lane = t & 63;
  if (lane == 0) { redf[wave][0]=vmax_t; redf[wave][1]=vmin_t;
                   redf[wave][2]=vmax_p; redf[wave][3]=vmin_p; }
  __syncthreads();
  if (t == 0) {
    float mxt=redf[0][0], mnt=redf[0][1], mxp=redf[0][2], mnp=redf[0][3];
    for (int wv = 1; wv < 4; ++wv) {
      mxt = fmaxf(mxt, redf[wv][0]); mnt = fminf(mnt, redf[wv][1]);
      mxp = fmaxf(mxp, redf[wv][2]); mnp = fminf(mnp, redf[wv][3]);
    }
    // max via bits (0-init identity); min via ~bits (0-init identity)
    atomicMax(&rmm_u[img*2 + 0],     __float_as_uint(mxt));
    atomicMax(&rmm_u[img*2 + 1],     ~__float_as_uint(mnt));
    atomicMax(&rmm_u[(4+img)*2 + 0], __float_as_uint(mxp));
    atomicMax(&rmm_u[(4+img)*2 + 1], ~__float_as_uint(mnp));
    // per-image sub-barrier: release RMW orders the atomics above (all at
    // LLC already — nothing dirty in L2; round-5's wbl2 disaster avoided)
    __hip_atomic_fetch_add(&cnts[10+img], 1u, __ATOMIC_RELEASE,
                           __HIP_MEMORY_SCOPE_AGENT);
    while (__hip_atomic_load(&cnts[10+img], __ATOMIC_RELAXED,
                             __HIP_MEMORY_SCOPE_AGENT) < 32u)
      __builtin_amdgcn_s_sleep(2);
  }
  __syncthreads();
  if (t < 4) {
    int idx = (t < 2) ? (img*2 + t) : ((4+img)*2 + (t-2));
    smm[t] = __hip_atomic_load(&rmm_u[idx], __ATOMIC_RELAXED,
                               __HIP_MEMORY_SCOPE_AGENT);
  }
  __syncthreads();
  float rmax_t = fmaxf(__uint_as_float( smm[0]), 1.0f);
  float rmin_t = fmaxf(__uint_as_float(~smm[1]), 1.0f);
  float rmax_p = fmaxf(__uint_as_float( smm[2]), 1.0f);
  float rmin_p = fmaxf(__uint_as_float(~smm[3]), 1.0f);

  // --- q-phase over this block's OWN 2048 pixels (dist in regs) ---
  float q1 = 0.f, q2 = 0.f, q3 = 0.f, q4 = 0.f;
#pragma unroll
  for (int j = 0; j < 8; ++j) {
    int y = yg * 8 + j;
    float xv = y_pred[img*NPIX + y*W + x0 + xq];
    float p = 1.0f / (1.0f + expf(-xv));
    float ppv = 1.0f / (1.0f + expf(-(2.0f * p - 1.0f)));  // exact ref expr
    int b = sh0 + xq;
    int m_t  = (int)((SA[y][kx] >> b) & 1ULL);   // true mask from LDS
    int s_t  = (int)((srow_t[y] >> b) & 1ULL);
    int s_pb = (int)((srow_p[y] >> b) & 1ULL);
    // --- true branch (binary) ---
    float distances_t = m_t ? dist_t[j] : 0.0f;
    float skelrad_t   = s_t ? distances_t : 0.0f;
    float dmn_t = fminf(distances_t, rmax_t) / rmax_t;
    float srn_t = skelrad_t / rmax_t;
    float In_t  = s_t ? (rmax_t - skelrad_t + rmin_t) / rmax_t : 0.0f;
    float q_vl   = m_t ? dmn_t : 0.0f;
    float q_slvl = m_t ? srn_t : 0.0f;
    float q_sl   = s_t ? In_t  : 0.0f;
    // --- pred branch (probabilistic) ---
    float skel_in_p = s_pb ? ppv : 0.0f;      // skel_pred_prob
    bool msk_p = ppv > 0.5f;
    bool sk_p  = skel_in_p > 0.5f;
    float distances_p = msk_p ? dist_p[j] : 0.0f;
    float skelrad_p   = sk_p ? distances_p : 0.0f;
    float dmn_p = fminf(distances_p, rmax_p) / rmax_p;
    float srn_p = skelrad_p / rmax_p;
    float In_p  = sk_p ? (rmax_p - skelrad_p + rmin_p) / rmax_p : 0.0f;
    float q_vp   = dmn_p * ppv;
    float q_spvp = srn_p * ppv;
    float q_sp   = In_p * skel_in_p;
    q1 += q_sp * q_vl;
    q2 += (q_spvp != 0.0f && q_slvl == 0.0f) ? q_spvp * q_sp : q_slvl * q_sp;
    q3 += q_sl * q_vp;
    q4 += (q_slvl != 0.0f && q_spvp == 0.0f) ? q_slvl * q_sl : q_spvp * q_sl;
  }
  for (int o = 32; o > 0; o >>= 1) {
    q1 += __shfl_down(q1, o, 64);
    q2 += __shfl_down(q2, o, 64);
    q3 += __shfl_down(q3, o, 64);
    q4 += __shfl_down(q4, o, 64);
  }
  if (lane == 0) { redf[wave][0]=q1; redf[wave][1]=q2; redf[wave][2]=q3; redf[wave][3]=q4; }
  __syncthreads();
  if (t == 0) {
    float a0=0,a1=0,a2=0,a3=0;
    for (int wv = 0; wv < 4; ++wv) {
      a0 += redf[wv][0]; a1 += redf[wv][1]; a2 += redf[wv][2]; a3 += redf[wv][3];
    }
    atomicAdd(&sums[0], (double)a0);
    atomicAdd(&sums[1], (double)a1);
    atomicAdd(&sums[2], (double)a2);
    atomicAdd(&sums[3], (double)a3);
    __threadfence();                    // publish sums before counting done
    unsigned c = atomicAdd(&cnts[8], 1u);
    if (c == NTILE - 1) {               // last block finalizes (device-scope
      double s0 = atomicAdd(&sums[0], 0.0);   // atomic loads for coherence)
      double s1 = atomicAdd(&sums[1], 0.0);
      double s2 = atomicAdd(&sums[2], 0.0);
      double s3 = atomicAdd(&sums[3], 0.0);
      double wp  = (s0 + 1.0) / (s1 + 1.0);
      double wsn = (s2 + 1.0) / (s3 + 1.0);
      out[0] = (float)(1.0 - 2.0 * (wp * wsn) / (wp + wsn));
    }
  }
}

extern "C" void kernel_launch(void* const* d_in, const int* in_sizes, int n_in,
                              void* d_out, int out_size, void* d_ws, size_t ws_size,
                              hipStream_t stream) {
  (void)in_sizes; (void)n_in; (void)out_size; (void)ws_size;
  const float* y_pred = (const float*)d_in[0];
  const int*   y_true = (const int*)d_in[1];
  float* out = (float*)d_out;
  char* ws = (char*)d_ws;

  // workspace layout (bytes) — only skel_bits + 160 B of control state
  u64*   skel_bits = (u64*)  (ws + 0);          // 8192 u64 (65,536 B)
  unsigned* rmm_u  = (unsigned*)(ws + 65536);   // 16 u32: [bi*2]=max bits, [bi*2+1]=max ~bits (min)
  double* sums     = (double*)(ws + 65600);     // 4 d (8-aligned)
  unsigned* cnts   = (unsigned*)(ws + 65632);   // [0..7] skel flags, [8] done, [10..13] img barriers

  // zero-init all control state (graph-safe; encodings make 0 the identity)
  hipMemsetAsync(ws + 65536, 0, 160, stream);
  fused_kernel<<<NB, 256, 0, stream>>>(y_pred, y_true, skel_bits, rmm_u, sums, cnts, out);
}